// Round 3
// baseline (58.737 us; speedup 1.0000x reference)
//
#include <hip/hip_runtime.h>

// x [E=512][N=65536] fp32.
//   sum_abs[col] = sum_{e>=1} |x[e][col]|
//   lb = x0 - sum_abs; ub = x0 + sum_abs
//   crossing = lb<=0 && ub>=0 ; dead = ub<=0
//   alpha = crossing ? 1-lb : 1
//   out[0]   = dead?0 : crossing? alpha*x0 - alpha*lb*0.5 : x0
//   out[e>0] = dead?0 : crossing? alpha*x : x
//
// Single-pass, REGISTER-staged: each block owns a 32-column slab; each thread
// holds its 16 float4 row-values in registers across the reduction barrier.
// Only a 4.2 KiB LDS reduction buffer -> occupancy VGPR-limited (~16-20
// waves/CU) instead of LDS-limited (8 waves/CU).

#define EROWS 512
#define W4 8                    // float4 column-groups per block (32 cols)
#define BLK 256
#define RSTRIDE (BLK / W4)      // 32 rows between a thread's samples
#define RPT (EROWS / RSTRIDE)   // 16 float4 per thread

__global__ __launch_bounds__(BLK, 4) void ar_fused(const float* __restrict__ x,
                                                   float* __restrict__ out, int n4) {
    __shared__ float4 part[BLK];     // per-thread partial |x| sums (4 KiB)
    __shared__ float4 scale4[W4];

    int t = threadIdx.x;
    int cseg  = t & (W4 - 1);        // 0..7  fixed float4 col group
    int rbase = t >> 3;              // 0..31 starting row
    int col4 = blockIdx.x * W4 + cseg;

    const float4* xv = (const float4*)x;
    float4* ov = (float4*)out;

    // ---- single global read into registers + |x| accumulate (row 0 excluded)
    float4 v[RPT];
    #pragma unroll
    for (int k = 0; k < RPT; ++k)
        v[k] = xv[(size_t)(rbase + k * RSTRIDE) * n4 + col4];

    float4 acc;
    if (rbase == 0) {                // v[0] is the center row: exclude
        acc.x = 0.f; acc.y = 0.f; acc.z = 0.f; acc.w = 0.f;
    } else {
        acc.x = fabsf(v[0].x); acc.y = fabsf(v[0].y);
        acc.z = fabsf(v[0].z); acc.w = fabsf(v[0].w);
    }
    #pragma unroll
    for (int k = 1; k < RPT; ++k) {
        acc.x += fabsf(v[k].x); acc.y += fabsf(v[k].y);
        acc.z += fabsf(v[k].z); acc.w += fabsf(v[k].w);
    }
    part[t] = acc;
    __syncthreads();

    // ---- finalize: 8 threads, one per float4 col group (they hold row 0 in v[0])
    if (t < W4) {
        float4 s = {0.f, 0.f, 0.f, 0.f};
        for (int j = 0; j < RSTRIDE; ++j) {
            float4 p = part[j * W4 + t];
            s.x += p.x; s.y += p.y; s.z += p.z; s.w += p.w;
        }
        float x0[4] = {v[0].x, v[0].y, v[0].z, v[0].w};
        float sm[4] = {s.x, s.y, s.z, s.w};
        float sc[4], o0[4];
        #pragma unroll
        for (int j = 0; j < 4; ++j) {
            float lb = x0[j] - sm[j];
            float ub = x0[j] + sm[j];
            bool crossing = (lb <= 0.f) && (ub >= 0.f);
            bool dead = (ub <= 0.f);
            float alpha = crossing ? (1.f - lb) : 1.f;
            float scl = dead ? 0.f : (crossing ? alpha : 1.f);
            float addv = (crossing && !dead) ? (-alpha * lb * 0.5f) : 0.f;
            sc[j] = scl;
            o0[j] = scl * x0[j] + addv;
        }
        float4 scv = {sc[0], sc[1], sc[2], sc[3]};
        float4 o0v = {o0[0], o0[1], o0[2], o0[3]};
        scale4[t] = scv;
        ov[col4] = o0v;              // row 0 output
    }
    __syncthreads();

    // ---- rescale register data, write out (threads t<8 skip k=0: row 0 done)
    float4 s = scale4[cseg];
    if (rbase != 0) {
        float4 o;
        o.x = v[0].x * s.x; o.y = v[0].y * s.y;
        o.z = v[0].z * s.z; o.w = v[0].w * s.w;
        ov[(size_t)rbase * n4 + col4] = o;
    }
    #pragma unroll
    for (int k = 1; k < RPT; ++k) {
        float4 o;
        o.x = v[k].x * s.x; o.y = v[k].y * s.y;
        o.z = v[k].z * s.z; o.w = v[k].w * s.w;
        ov[(size_t)(rbase + k * RSTRIDE) * n4 + col4] = o;
    }
}

extern "C" void kernel_launch(void* const* d_in, const int* in_sizes, int n_in,
                              void* d_out, int out_size, void* d_ws, size_t ws_size,
                              hipStream_t stream) {
    const float* x = (const float*)d_in[0];
    float* out = (float*)d_out;
    int total = in_sizes[0];     // 512 * 65536
    int N = total / EROWS;       // 65536
    int n4 = N >> 2;             // 16384 float4 per row
    int nblocks = n4 / W4;       // 2048

    ar_fused<<<nblocks, BLK, 0, stream>>>(x, out, n4);
}